// Round 3
// baseline (363.971 us; speedup 1.0000x reference)
//
#include <hip/hip_runtime.h>

// BloomStageLoss: label-smoothed CE + transition penalty, scalar mean.
// B = 4194304 rows x C=5 fp32 logits + int32 targets -> 1 float.
// ~100 MB read => ~16-19 us HBM floor at 6.3 TB/s achievable.
//
// R2 theory: R1 (72us) was latency-bound, NOT traffic-bound (L3-warm replays
// identical 72us). Cause: 1024 blocks x 16 serial barrier-coupled iterations.
// Fix: ONE tile per block (4096 blocks, 16384 waves, 7 blocks/CU co-resident)
// -> no loop-carried latency chain, latency hidden by block-level overlap.

constexpr int C = 5;
constexpr int BLOCK = 256;
constexpr int ROWS_PER_TILE = 4 * BLOCK;              // 1024 rows / block
constexpr int F4_PER_TILE = ROWS_PER_TILE * C / 4;    // 1280 float4 = 20 KB

__device__ __forceinline__ float trans_w(int d) {
    // |d| -> {0:0, 1:0.5, 2:1.0, >=3:2.0}  ==  (|d|>=3) ? 2 : 0.5*|d|
    d = d < 0 ? -d : d;
    return (d >= 3) ? 2.0f : 0.5f * (float)d;
}

__device__ __forceinline__ float row_loss(float a0, float a1, float a2,
                                          float a3, float a4, int t) {
    float m = fmaxf(fmaxf(fmaxf(a0, a1), fmaxf(a2, a3)), a4);
    float e0 = __expf(a0 - m);
    float e1 = __expf(a1 - m);
    float e2 = __expf(a2 - m);
    float e3 = __expf(a3 - m);
    float e4 = __expf(a4 - m);
    float s  = e0 + e1 + e2 + e3 + e4;
    float ls = __logf(s);
    float inv = 1.0f / s;

    float lp0 = a0 - m - ls;
    float lp1 = a1 - m - ls;
    float lp2 = a2 - m - ls;
    float lp3 = a3 - m - ls;
    float lp4 = a4 - m - ls;
    float sumlp = lp0 + lp1 + lp2 + lp3 + lp4;
    float lpt = (t == 0) ? lp0 : (t == 1) ? lp1 : (t == 2) ? lp2
              : (t == 3) ? lp3 : lp4;

    float pen = e0 * trans_w(t)     + e1 * trans_w(t - 1) + e2 * trans_w(t - 2)
              + e3 * trans_w(t - 3) + e4 * trans_w(t - 4);
    pen *= inv;

    // smoothing 0.1: 0.875*lpt + 0.025*sumlp
    return -(0.875f * lpt + 0.025f * sumlp) + 0.1f * pen;
}

__global__ __launch_bounds__(BLOCK) void bloom_fused(
        const float* __restrict__ x, const int* __restrict__ tgt,
        double* __restrict__ partial, unsigned int* __restrict__ counter,
        float* __restrict__ out, int nTiles, int B) {
    __shared__ float4 tile4[F4_PER_TILE];   // 20 KB
    __shared__ double wsum[4];
    __shared__ bool isLast;

    const int tid = threadIdx.x;
    const int tile = blockIdx.x;
    float local = 0.0f;

    if (tile < nTiles) {
        const float4* __restrict__ x4 = (const float4*)x;
        const long base4 = (long)tile * F4_PER_TILE;
        // perfectly coalesced lane-contiguous dwordx4; all 6 loads independent
        float4 v0 = x4[base4 + 0 * BLOCK + tid];
        float4 v1 = x4[base4 + 1 * BLOCK + tid];
        float4 v2 = x4[base4 + 2 * BLOCK + tid];
        float4 v3 = x4[base4 + 3 * BLOCK + tid];
        float4 v4 = x4[base4 + 4 * BLOCK + tid];
        int4 t4 = ((const int4*)tgt)[(long)tile * BLOCK + tid];

        tile4[0 * BLOCK + tid] = v0;
        tile4[1 * BLOCK + tid] = v1;
        tile4[2 * BLOCK + tid] = v2;
        tile4[3 * BLOCK + tid] = v3;
        tile4[4 * BLOCK + tid] = v4;
        __syncthreads();

        // this thread's 4 rows = 20 contiguous floats (stride-5 float4:
        // measured 0 bank conflicts in R1)
        float4 r0 = tile4[tid * 5 + 0];
        float4 r1 = tile4[tid * 5 + 1];
        float4 r2 = tile4[tid * 5 + 2];
        float4 r3 = tile4[tid * 5 + 3];
        float4 r4 = tile4[tid * 5 + 4];

        local  = row_loss(r0.x, r0.y, r0.z, r0.w, r1.x, t4.x);
        local += row_loss(r1.y, r1.z, r1.w, r2.x, r2.y, t4.y);
        local += row_loss(r2.z, r2.w, r3.x, r3.y, r3.z, t4.z);
        local += row_loss(r3.w, r4.x, r4.y, r4.z, r4.w, t4.w);
    }

    // tail rows (B % ROWS_PER_TILE) -> last block
    if (blockIdx.x == gridDim.x - 1) {
        for (int r = nTiles * ROWS_PER_TILE + tid; r < B; r += BLOCK) {
            local += row_loss(x[(long)r * C + 0], x[(long)r * C + 1],
                              x[(long)r * C + 2], x[(long)r * C + 3],
                              x[(long)r * C + 4], tgt[r]);
        }
    }

    // block reduction
    #pragma unroll
    for (int off = 32; off > 0; off >>= 1)
        local += __shfl_down(local, off, 64);
    const int lane = tid & 63;
    const int wid = tid >> 6;
    if (lane == 0) wsum[wid] = (double)local;
    __syncthreads();

    if (tid == 0) {
        double bs = wsum[0] + wsum[1] + wsum[2] + wsum[3];
        __hip_atomic_store(&partial[blockIdx.x], bs,
                           __ATOMIC_RELAXED, __HIP_MEMORY_SCOPE_AGENT);
        __threadfence();
        unsigned prev = __hip_atomic_fetch_add(counter, 1u, __ATOMIC_ACQ_REL,
                                               __HIP_MEMORY_SCOPE_AGENT);
        isLast = (prev == (unsigned)(gridDim.x - 1));
    }
    __syncthreads();

    if (isLast) {   // block-uniform: final reduce of per-block partials
        __threadfence();
        double s = 0.0;
        for (int i = tid; i < (int)gridDim.x; i += BLOCK)
            s += __hip_atomic_load(&partial[i], __ATOMIC_RELAXED,
                                   __HIP_MEMORY_SCOPE_AGENT);
        #pragma unroll
        for (int off = 32; off > 0; off >>= 1)
            s += __shfl_down(s, off, 64);
        if (lane == 0) wsum[wid] = s;
        __syncthreads();
        if (tid == 0)
            out[0] = (float)((wsum[0] + wsum[1] + wsum[2] + wsum[3]) / (double)B);
    }
}

extern "C" void kernel_launch(void* const* d_in, const int* in_sizes, int n_in,
                              void* d_out, int out_size, void* d_ws, size_t ws_size,
                              hipStream_t stream) {
    const float* x = (const float*)d_in[0];
    const int* tgt = (const int*)d_in[1];
    float* out = (float*)d_out;

    int B = in_sizes[1];
    int nTiles = B / ROWS_PER_TILE;       // 4096 for B = 4194304
    int blocks = (nTiles > 0) ? nTiles : 1;

    double* partial = (double*)d_ws;
    unsigned int* counter = (unsigned int*)((char*)d_ws + blocks * sizeof(double));

    hipMemsetAsync(counter, 0, sizeof(unsigned int), stream);

    bloom_fused<<<blocks, BLOCK, 0, stream>>>(x, tgt, partial, counter, out,
                                              nTiles, B);
}

// Round 4
// 138.374 us; speedup vs baseline: 2.6303x; 2.6303x over previous
//
#include <hip/hip_runtime.h>

// BloomStageLoss: label-smoothed CE + transition penalty, scalar mean.
// B = 4194304 rows x C=5 fp32 logits + int32 targets -> 1 float.
// ~100 MB read => ~16-19 us HBM floor at 6.3 TB/s achievable.
//
// R3 theory: R0-R2 were all EPILOGUE-bound, not memory-bound. Per-block
// device-scope fences/atomics serialize at the TCC (~55ns each: 1024 -> 56us
// in R1, 4096 -> 233us in R2; R0's 16k same-address atomics -> 61us).
// Fix: NO fences, NO atomics. Kernel A plain-stores per-block partials
// (kernel-boundary ordering makes them visible), kernel B reduces them.

constexpr int C = 5;
constexpr int BLOCK = 256;
constexpr int ROWS_PER_TILE = 4 * BLOCK;              // 1024 rows / block
constexpr int F4_PER_TILE = ROWS_PER_TILE * C / 4;    // 1280 float4 = 20 KB

__device__ __forceinline__ float trans_w(int d) {
    // |d| -> {0:0, 1:0.5, 2:1.0, >=3:2.0}
    d = d < 0 ? -d : d;
    return (d >= 3) ? 2.0f : 0.5f * (float)d;
}

__device__ __forceinline__ float row_loss(float a0, float a1, float a2,
                                          float a3, float a4, int t) {
    float m = fmaxf(fmaxf(fmaxf(a0, a1), fmaxf(a2, a3)), a4);
    float e0 = __expf(a0 - m);
    float e1 = __expf(a1 - m);
    float e2 = __expf(a2 - m);
    float e3 = __expf(a3 - m);
    float e4 = __expf(a4 - m);
    float s  = e0 + e1 + e2 + e3 + e4;
    float ls = __logf(s);
    float inv = 1.0f / s;

    float lp0 = a0 - m - ls;
    float lp1 = a1 - m - ls;
    float lp2 = a2 - m - ls;
    float lp3 = a3 - m - ls;
    float lp4 = a4 - m - ls;
    float sumlp = lp0 + lp1 + lp2 + lp3 + lp4;
    float lpt = (t == 0) ? lp0 : (t == 1) ? lp1 : (t == 2) ? lp2
              : (t == 3) ? lp3 : lp4;

    float pen = e0 * trans_w(t)     + e1 * trans_w(t - 1) + e2 * trans_w(t - 2)
              + e3 * trans_w(t - 3) + e4 * trans_w(t - 4);
    pen *= inv;

    // smoothing 0.1: 0.875*lpt + 0.025*sumlp
    return -(0.875f * lpt + 0.025f * sumlp) + 0.1f * pen;
}

__global__ __launch_bounds__(BLOCK) void bloom_partial(
        const float* __restrict__ x, const int* __restrict__ tgt,
        double* __restrict__ partial, int nTiles, int B) {
    __shared__ float4 tile4[F4_PER_TILE];   // 20 KB
    __shared__ double wsum[4];

    const int tid = threadIdx.x;
    const int tile = blockIdx.x;
    float local = 0.0f;

    if (tile < nTiles) {
        const float4* __restrict__ x4 = (const float4*)x;
        const long base4 = (long)tile * F4_PER_TILE;
        // perfectly coalesced lane-contiguous dwordx4; all 6 loads independent
        float4 v0 = x4[base4 + 0 * BLOCK + tid];
        float4 v1 = x4[base4 + 1 * BLOCK + tid];
        float4 v2 = x4[base4 + 2 * BLOCK + tid];
        float4 v3 = x4[base4 + 3 * BLOCK + tid];
        float4 v4 = x4[base4 + 4 * BLOCK + tid];
        int4 t4 = ((const int4*)tgt)[(long)tile * BLOCK + tid];

        tile4[0 * BLOCK + tid] = v0;
        tile4[1 * BLOCK + tid] = v1;
        tile4[2 * BLOCK + tid] = v2;
        tile4[3 * BLOCK + tid] = v3;
        tile4[4 * BLOCK + tid] = v4;
        __syncthreads();

        // this thread's 4 rows = 20 contiguous floats (stride-5 float4:
        // measured 0 bank conflicts)
        float4 r0 = tile4[tid * 5 + 0];
        float4 r1 = tile4[tid * 5 + 1];
        float4 r2 = tile4[tid * 5 + 2];
        float4 r3 = tile4[tid * 5 + 3];
        float4 r4 = tile4[tid * 5 + 4];

        local  = row_loss(r0.x, r0.y, r0.z, r0.w, r1.x, t4.x);
        local += row_loss(r1.y, r1.z, r1.w, r2.x, r2.y, t4.y);
        local += row_loss(r2.z, r2.w, r3.x, r3.y, r3.z, t4.z);
        local += row_loss(r3.w, r4.x, r4.y, r4.z, r4.w, t4.w);
    }

    // tail rows (B % ROWS_PER_TILE) -> last block
    if (blockIdx.x == gridDim.x - 1) {
        for (int r = nTiles * ROWS_PER_TILE + tid; r < B; r += BLOCK) {
            local += row_loss(x[(long)r * C + 0], x[(long)r * C + 1],
                              x[(long)r * C + 2], x[(long)r * C + 3],
                              x[(long)r * C + 4], tgt[r]);
        }
    }

    // block reduction; PLAIN store of the partial (no fence, no atomic —
    // kernel boundary orders it before bloom_final)
    #pragma unroll
    for (int off = 32; off > 0; off >>= 1)
        local += __shfl_down(local, off, 64);
    const int lane = tid & 63;
    const int wid = tid >> 6;
    if (lane == 0) wsum[wid] = (double)local;
    __syncthreads();
    if (tid == 0)
        partial[blockIdx.x] = wsum[0] + wsum[1] + wsum[2] + wsum[3];
}

__global__ __launch_bounds__(BLOCK) void bloom_final(
        const double* __restrict__ partial, float* __restrict__ out,
        int nPartials, int B) {
    __shared__ double wsum[4];
    const int tid = threadIdx.x;
    double s = 0.0;
    for (int i = tid; i < nPartials; i += BLOCK)
        s += partial[i];
    #pragma unroll
    for (int off = 32; off > 0; off >>= 1)
        s += __shfl_down(s, off, 64);
    const int lane = tid & 63;
    const int wid = tid >> 6;
    if (lane == 0) wsum[wid] = s;
    __syncthreads();
    if (tid == 0)
        out[0] = (float)((wsum[0] + wsum[1] + wsum[2] + wsum[3]) / (double)B);
}

extern "C" void kernel_launch(void* const* d_in, const int* in_sizes, int n_in,
                              void* d_out, int out_size, void* d_ws, size_t ws_size,
                              hipStream_t stream) {
    const float* x = (const float*)d_in[0];
    const int* tgt = (const int*)d_in[1];
    float* out = (float*)d_out;

    int B = in_sizes[1];
    int nTiles = B / ROWS_PER_TILE;       // 4096 for B = 4194304
    int blocks = (nTiles > 0) ? nTiles : 1;

    double* partial = (double*)d_ws;

    bloom_partial<<<blocks, BLOCK, 0, stream>>>(x, tgt, partial, nTiles, B);
    bloom_final<<<1, BLOCK, 0, stream>>>(partial, out, blocks, B);
}

// Round 5
// 137.278 us; speedup vs baseline: 2.6513x; 1.0080x over previous
//
#include <hip/hip_runtime.h>

// BloomStageLoss: label-smoothed CE + transition penalty, scalar mean.
// B = 4194304 rows x C=5 fp32 logits + int32 targets -> 1 float.
// ~100 MB read => ~17 us floor at 6.3 TB/s.
//
// R4 post-mortem: fence/atomic removal confirmed (364->138us); our kernels
// fell out of rocprof top-5 (<49us). Top-5 is now harness ws-poison/restore
// (~100us/iter, invariant across rounds, outside our control).
// R5: drop LDS staging + mid-kernel barrier. Direct strided float4 loads:
// every byte of each line is consumed within the wave (R0: FETCH=50MB, no
// over-fetch), and 10 independent dwordx4/thread maximizes MLP with no
// barrier stall. 2048 blocks x 256 thr x 8 rows = exactly B.

constexpr int C = 5;
constexpr int BLOCK = 256;
constexpr int ROWS_PER_THREAD = 8;                    // 10 float4 per thread
constexpr int ROWS_PER_BLOCK = BLOCK * ROWS_PER_THREAD;

__device__ __forceinline__ float trans_w(int d) {
    // |d| -> {0:0, 1:0.5, 2:1.0, >=3:2.0}
    d = d < 0 ? -d : d;
    return (d >= 3) ? 2.0f : 0.5f * (float)d;
}

__device__ __forceinline__ float row_loss(float a0, float a1, float a2,
                                          float a3, float a4, int t) {
    float m = fmaxf(fmaxf(fmaxf(a0, a1), fmaxf(a2, a3)), a4);
    float e0 = __expf(a0 - m);
    float e1 = __expf(a1 - m);
    float e2 = __expf(a2 - m);
    float e3 = __expf(a3 - m);
    float e4 = __expf(a4 - m);
    float s  = e0 + e1 + e2 + e3 + e4;
    float ls = __logf(s);
    float inv = 1.0f / s;

    float lp0 = a0 - m - ls;
    float lp1 = a1 - m - ls;
    float lp2 = a2 - m - ls;
    float lp3 = a3 - m - ls;
    float lp4 = a4 - m - ls;
    float sumlp = lp0 + lp1 + lp2 + lp3 + lp4;
    float lpt = (t == 0) ? lp0 : (t == 1) ? lp1 : (t == 2) ? lp2
              : (t == 3) ? lp3 : lp4;

    float pen = e0 * trans_w(t)     + e1 * trans_w(t - 1) + e2 * trans_w(t - 2)
              + e3 * trans_w(t - 3) + e4 * trans_w(t - 4);
    pen *= inv;

    // smoothing 0.1: 0.875*lpt + 0.025*sumlp
    return -(0.875f * lpt + 0.025f * sumlp) + 0.1f * pen;
}

// 4 consecutive rows packed in 5 float4s -> accumulate their losses
__device__ __forceinline__ float quad_loss(float4 v0, float4 v1, float4 v2,
                                           float4 v3, float4 v4, int4 t) {
    float r;
    r  = row_loss(v0.x, v0.y, v0.z, v0.w, v1.x, t.x);
    r += row_loss(v1.y, v1.z, v1.w, v2.x, v2.y, t.y);
    r += row_loss(v2.z, v2.w, v3.x, v3.y, v3.z, t.z);
    r += row_loss(v3.w, v4.x, v4.y, v4.z, v4.w, t.w);
    return r;
}

__global__ __launch_bounds__(BLOCK) void bloom_partial(
        const float* __restrict__ x, const int* __restrict__ tgt,
        double* __restrict__ partial, int nGroups, int B) {
    const int tid = threadIdx.x;
    const int g = blockIdx.x * BLOCK + tid;   // 8-row group index
    float local = 0.0f;

    if (g < nGroups) {
        const float4* __restrict__ x4 = (const float4*)x;
        const int4* __restrict__ tgt4 = (const int4*)tgt;
        const long b4 = (long)g * 10;         // 8 rows * 5 floats = 10 float4
        // 12 independent loads issued back-to-back (deep MLP, no barrier)
        float4 v0 = x4[b4 + 0];
        float4 v1 = x4[b4 + 1];
        float4 v2 = x4[b4 + 2];
        float4 v3 = x4[b4 + 3];
        float4 v4 = x4[b4 + 4];
        float4 v5 = x4[b4 + 5];
        float4 v6 = x4[b4 + 6];
        float4 v7 = x4[b4 + 7];
        float4 v8 = x4[b4 + 8];
        float4 v9 = x4[b4 + 9];
        int4 ta = tgt4[(long)g * 2 + 0];
        int4 tb = tgt4[(long)g * 2 + 1];

        local  = quad_loss(v0, v1, v2, v3, v4, ta);
        local += quad_loss(v5, v6, v7, v8, v9, tb);
    }

    // tail rows (B % ROWS_PER_THREAD*BLOCK) -> last block, scalar per row
    if (blockIdx.x == gridDim.x - 1) {
        for (int r = nGroups * ROWS_PER_THREAD + tid; r < B; r += BLOCK) {
            local += row_loss(x[(long)r * C + 0], x[(long)r * C + 1],
                              x[(long)r * C + 2], x[(long)r * C + 3],
                              x[(long)r * C + 4], tgt[r]);
        }
    }

    // block reduction; plain store (kernel boundary orders it before final)
    #pragma unroll
    for (int off = 32; off > 0; off >>= 1)
        local += __shfl_down(local, off, 64);
    __shared__ double wsum[4];
    const int lane = tid & 63;
    const int wid = tid >> 6;
    if (lane == 0) wsum[wid] = (double)local;
    __syncthreads();
    if (tid == 0)
        partial[blockIdx.x] = wsum[0] + wsum[1] + wsum[2] + wsum[3];
}

__global__ __launch_bounds__(BLOCK) void bloom_final(
        const double* __restrict__ partial, float* __restrict__ out,
        int nPartials, int B) {
    __shared__ double wsum[4];
    const int tid = threadIdx.x;
    double s = 0.0;
    for (int i = tid; i < nPartials; i += BLOCK)
        s += partial[i];
    #pragma unroll
    for (int off = 32; off > 0; off >>= 1)
        s += __shfl_down(s, off, 64);
    const int lane = tid & 63;
    const int wid = tid >> 6;
    if (lane == 0) wsum[wid] = s;
    __syncthreads();
    if (tid == 0)
        out[0] = (float)((wsum[0] + wsum[1] + wsum[2] + wsum[3]) / (double)B);
}

extern "C" void kernel_launch(void* const* d_in, const int* in_sizes, int n_in,
                              void* d_out, int out_size, void* d_ws, size_t ws_size,
                              hipStream_t stream) {
    const float* x = (const float*)d_in[0];
    const int* tgt = (const int*)d_in[1];
    float* out = (float*)d_out;

    int B = in_sizes[1];
    int nGroups = B / ROWS_PER_THREAD;                    // 8-row groups
    int blocks = (nGroups + BLOCK - 1) / BLOCK;           // 2048 for B=4M
    if (blocks < 1) blocks = 1;

    double* partial = (double*)d_ws;

    bloom_partial<<<blocks, BLOCK, 0, stream>>>(x, tgt, partial, nGroups, B);
    bloom_final<<<1, BLOCK, 0, stream>>>(partial, out, blocks, B);
}